// Round 13
// baseline (3681.999 us; speedup 1.0000x reference)
//
#include <hip/hip_runtime.h>

// LSTM_87771951661891: persistent kernel, wave-autonomous + XCD-local data.
// Proven-parts recombination:
//  - static XCD-pure groups (R11: bid%8==XCD; FETCH collapse proved purity)
//  - h data exchange: sc0-only stores/loads, local-L2 coherent (R11-proven)
//  - flags: agent-scope relaxed atomics at MALL (R5-R8,R11-proven; sc0 flags
//    hang - R9/R10/R12). Producer orders data->flag via s_waitcnt vmcnt(0).
//  - R7 wave-autonomous structure: each wave direct-loads its 16 B-fragments
//    (no LDS staging, no __syncthreads in the loop); 4x read redundancy is
//    cheap on local L2 (~0.4us/step aggregate).
//  - in-wave __shfl transpose for the h_new store (replaces LDS patch hop)
//  - inactive-group skip: bs descending => once row0 >= bs_t the group stops
//    syncing entirely (zero-fill out, registers carry state). Group-internal.

#define TN 512
#define BM 256
#define HD 512
#define ID 256

typedef __attribute__((ext_vector_type(8))) __bf16 bf16x8;
typedef __attribute__((ext_vector_type(4))) __bf16 bf16x4;
typedef __attribute__((ext_vector_type(4))) unsigned int u32x4;
typedef __attribute__((ext_vector_type(4))) float f32x4;

union ABits { u32x4 u; bf16x8 b; };
union U64x1 { bf16x4 v; unsigned long long q; };

__device__ __forceinline__ float sigm(float x) { return 1.f / (1.f + __expf(-x)); }
__device__ __forceinline__ float tanh_fast(float x) { return 1.f - 2.f / (__expf(2.f * x) + 1.f); }

// sc0-only 8B store: dirty line in the LOCAL XCD L2 (group coherence point)
__device__ __forceinline__ void store_h64(__bf16* p, unsigned long long v) {
    asm volatile("global_store_dwordx2 %0, %1, off sc0" :: "v"(p), "v"(v) : "memory");
}

__global__ void __launch_bounds__(256, 1)
lstm_persist(const float* __restrict__ x_in, const int* __restrict__ bs_in,
             const float* __restrict__ h0, const float* __restrict__ c0,
             const float* __restrict__ tau_p, const float* __restrict__ Ww,
             const float* __restrict__ Wb, const float* __restrict__ Uw,
             float* __restrict__ out, __bf16* __restrict__ hbuf,
             int* __restrict__ flags)
{
    __shared__ int   bs_lds[TN];
    __shared__ float x0_lds[16][ID + 1];   // prologue only

    const int tid  = threadIdx.x;
    const int lane = tid & 63;
    const int w    = tid >> 6;             // wave 0..3
    const int bid  = blockIdx.x;

    // static XCD-pure grouping (R11-proven): XCD x = bid&7, in-XCD idx = bid>>3
    const int xcd = bid & 7;
    const int ii  = bid >> 3;
    const int mg  = xcd * 2 + (ii >> 4);   // sync-group (16 blocks, one XCD)
    const int jb  = ii & 15;               // j-block within group

    const int row0 = mg * 16;
    const int j0   = jb * 32;
    const int l15  = lane & 15;            // MFMA row (m) / B-frag col
    const int kg   = lane >> 4;            // k-chunk id; hidden-subcol in output
    const int gq   = lane & 3;             // ub build
    const int jjq  = l15 >> 2;             // ub build
    const float tau = tau_p[0];

    // ---------------- prologue ----------------
    for (int i = tid; i < TN; i += 256) bs_lds[i] = bs_in[i];
    for (int s = tid; s < 16 * (ID / 4); s += 256) {
        int r = s >> 6, cs = s & 63;
        *reinterpret_cast<float4*>(&x0_lds[r][cs * 4]) =
            reinterpret_cast<const float4*>(x_in + (size_t)(row0 + r) * ID)[cs];
    }
    __syncthreads();

    // Gx = x0 @ Ww + Wb for this lane's 8 output gates
    float gxv[2][4];
    {
        float a[2][4] = {};
        const int cbase = j0 + 8 * w + kg;
        for (int k = 0; k < ID; ++k) {
            float xv = x0_lds[l15][k];
            const float* wr = Ww + (size_t)k * 2048;
            #pragma unroll
            for (int g = 0; g < 4; ++g) {
                a[0][g] += xv * wr[g * HD + cbase];
                a[1][g] += xv * wr[g * HD + cbase + 4];
            }
        }
        #pragma unroll
        for (int g = 0; g < 4; ++g) {
            gxv[0][g] = a[0][g] + Wb[g * HD + cbase];
            gxv[1][g] = a[1][g] + Wb[g * HD + cbase + 4];
        }
    }

    // U slice -> registers (A-operand = U^T)
    bf16x8 ub[2][16];
    #pragma unroll
    for (int f = 0; f < 2; ++f) {
        const int ucol = gq * HD + j0 + 8 * w + 4 * f + jjq;
        #pragma unroll
        for (int ki = 0; ki < 16; ++ki) {
            const int kb = ki * 32 + kg * 8;
            bf16x8 v;
            #pragma unroll
            for (int e = 0; e < 8; ++e) v[e] = (__bf16)Uw[(size_t)(kb + e) * 2048 + ucol];
            ub[f][ki] = v;
        }
    }

    // c state: lane-local, (row m=l15, col j0+8w+4f+kg)
    float creg[2];
    #pragma unroll
    for (int f = 0; f < 2; ++f)
        creg[f] = c0[(size_t)(row0 + l15) * HD + j0 + 8 * w + 4 * f + kg];

    // store-lane setup (lane<32): r=lane>>1, ss=lane&1 -> 4 cols jc..jc+3
    const int sr   = lane >> 1, ss = lane & 1;
    const int sr16 = (lane >> 1) & 15;     // safe shfl source row for all lanes
    const int jc   = j0 + 8 * w + 4 * ss;
    const bool is_store = (lane < 32);
    const bool owner = (jb == 0) && (w == 0) && (ss == 0) && is_store;
    float hprev[4] = {0.f, 0.f, 0.f, 0.f};
    float hxy0 = 0.f, hxy1 = 0.f;

    if (is_store) {
        float4 v = *reinterpret_cast<const float4*>(h0 + (size_t)(row0 + sr) * HD + jc);
        hprev[0] = v.x; hprev[1] = v.y; hprev[2] = v.z; hprev[3] = v.w;
        if (owner) { hxy0 = v.x; hxy1 = v.y; }
        U64x1 sv;
        #pragma unroll
        for (int c = 0; c < 4; ++c) sv.v[c] = (__bf16)hprev[c];
        store_h64(hbuf + (size_t)(row0 + sr) * HD + jc, sv.q);
    }
    asm volatile("s_waitcnt vmcnt(0)" ::: "memory");
    __builtin_amdgcn_sched_barrier(0);
    if (lane == 0)
        __hip_atomic_store(&flags[mg * 64 + jb * 4 + w], 1,
                           __ATOMIC_RELAXED, __HIP_MEMORY_SCOPE_AGENT);

    // ---------------- main sequential loop ----------------
    for (int t = 0; t < TN; ++t) {
        const __bf16* base_p = hbuf + (size_t)(t & 1) * (BM * HD);
        __bf16*       base_n = hbuf + (size_t)((t + 1) & 1) * (BM * HD);
        const int bs_t = bs_lds[t];

        // fp32 xcorr side-channel advance (owner lanes; harmless elsewhere)
        if (t != 0) {
            float xs0 = hxy0, xs1 = hxy1;
            hxy0 = xs0 + tau * (1.5f * xs0 + 0.66666667f * xs1);
            hxy1 = xs1 + tau * (-1.5f * xs0);
        }

        // group fully inactive (bs descending): no sync/exchange, zero out[t]
        if (row0 >= bs_t) {
            if (is_store) {
                float4 z = {0.f, 0.f, 0.f, 0.f};
                *reinterpret_cast<float4*>(out + (size_t)t * (BM * HD)
                                           + (size_t)(row0 + sr) * HD + jc) = z;
            }
            continue;
        }

        // spin: all 64 producer-wave flags >= t+1 (agent/MALL; bounded)
        for (int it = 0; it < (1 << 20); ++it) {
            int v = __hip_atomic_load(&flags[mg * 64 + lane],
                                      __ATOMIC_RELAXED, __HIP_MEMORY_SCOPE_AGENT);
            if (__all(v >= t + 1)) break;
            __builtin_amdgcn_s_sleep(1);
        }

        // per-wave direct sc0 loads (local L2) of the 16 B-fragments
        const __bf16* arow = base_p + (size_t)(row0 + l15) * HD + kg * 8;
        u32x4 r0,r1,r2,r3,r4,r5,r6,r7,r8,r9,r10,r11,r12,r13,r14,r15;
        asm volatile(
            "global_load_dwordx4 %0, %[p], off sc0\n\t"
            "global_load_dwordx4 %1, %[p], off offset:64 sc0\n\t"
            "global_load_dwordx4 %2, %[p], off offset:128 sc0\n\t"
            "global_load_dwordx4 %3, %[p], off offset:192 sc0\n\t"
            "global_load_dwordx4 %4, %[p], off offset:256 sc0\n\t"
            "global_load_dwordx4 %5, %[p], off offset:320 sc0\n\t"
            "global_load_dwordx4 %6, %[p], off offset:384 sc0\n\t"
            "global_load_dwordx4 %7, %[p], off offset:448 sc0\n\t"
            "global_load_dwordx4 %8, %[p], off offset:512 sc0\n\t"
            "global_load_dwordx4 %9, %[p], off offset:576 sc0\n\t"
            "global_load_dwordx4 %10, %[p], off offset:640 sc0\n\t"
            "global_load_dwordx4 %11, %[p], off offset:704 sc0\n\t"
            "global_load_dwordx4 %12, %[p], off offset:768 sc0\n\t"
            "global_load_dwordx4 %13, %[p], off offset:832 sc0\n\t"
            "global_load_dwordx4 %14, %[p], off offset:896 sc0\n\t"
            "global_load_dwordx4 %15, %[p], off offset:960 sc0\n\t"
            "s_waitcnt vmcnt(0)"
            : "=&v"(r0), "=&v"(r1), "=&v"(r2), "=&v"(r3),
              "=&v"(r4), "=&v"(r5), "=&v"(r6), "=&v"(r7),
              "=&v"(r8), "=&v"(r9), "=&v"(r10), "=&v"(r11),
              "=&v"(r12), "=&v"(r13), "=&v"(r14), "=&v"(r15)
            : [p] "v"(arow)
            : "memory");
        __builtin_amdgcn_sched_barrier(0);

        bf16x8 ah[16];
        {
            ABits tb;
            tb.u = r0;  ah[0]  = tb.b;  tb.u = r1;  ah[1]  = tb.b;
            tb.u = r2;  ah[2]  = tb.b;  tb.u = r3;  ah[3]  = tb.b;
            tb.u = r4;  ah[4]  = tb.b;  tb.u = r5;  ah[5]  = tb.b;
            tb.u = r6;  ah[6]  = tb.b;  tb.u = r7;  ah[7]  = tb.b;
            tb.u = r8;  ah[8]  = tb.b;  tb.u = r9;  ah[9]  = tb.b;
            tb.u = r10; ah[10] = tb.b;  tb.u = r11; ah[11] = tb.b;
            tb.u = r12; ah[12] = tb.b;  tb.u = r13; ah[13] = tb.b;
            tb.u = r14; ah[14] = tb.b;  tb.u = r15; ah[15] = tb.b;
        }

        // read-side xcorr on k=0,1 (all rows; t!=0), fp32
        if (t != 0 && kg == 0) {
            float xs0 = (float)ah[0][0];
            float xs1 = (float)ah[0][1];
            ah[0][0] = (__bf16)(xs0 + tau * (1.5f * xs0 + 0.66666667f * xs1));
            ah[0][1] = (__bf16)(xs1 + tau * (-1.5f * xs0));
        }

        // gates = U^T x h^T (swapped operands)
        f32x4 acc0 = {0.f, 0.f, 0.f, 0.f}, acc1 = {0.f, 0.f, 0.f, 0.f};
        #pragma unroll
        for (int ki = 0; ki < 16; ++ki) {
            acc0 = __builtin_amdgcn_mfma_f32_16x16x32_bf16(ub[0][ki], ah[ki], acc0, 0, 0, 0);
            acc1 = __builtin_amdgcn_mfma_f32_16x16x32_bf16(ub[1][ki], ah[ki], acc1, 0, 0, 0);
        }

        // pointwise: lane-local; keep hn for both f in registers
        const bool act_m = (row0 + l15) < bs_t;
        float hnf0, hnf1;
        {
            float gi = acc0[0] + gxv[0][0];
            float gf = acc0[1] + gxv[0][1];
            float gg = acc0[2] + gxv[0][2];
            float go = acc0[3] + gxv[0][3];
            float cn = sigm(gf) * creg[0] + sigm(gi) * tanh_fast(gg);
            hnf0 = sigm(go) * tanh_fast(cn);
            if (act_m) creg[0] = cn;
        }
        {
            float gi = acc1[0] + gxv[1][0];
            float gf = acc1[1] + gxv[1][1];
            float gg = acc1[2] + gxv[1][2];
            float go = acc1[3] + gxv[1][3];
            float cn = sigm(gf) * creg[1] + sigm(gi) * tanh_fast(gg);
            hnf1 = sigm(go) * tanh_fast(cn);
            if (act_m) creg[1] = cn;
        }

        // in-wave shfl transpose: store lane L (row r=L>>1, f=L&1) gathers
        // hn(r, 8w+4f+c) from lane 16c+r (value hnf0/hnf1)
        float av[4], bv[4];
        #pragma unroll
        for (int c = 0; c < 4; ++c) {
            av[c] = __shfl(hnf0, 16 * c + sr16);
            bv[c] = __shfl(hnf1, 16 * c + sr16);
        }

        // store phase: lanes 0..31 (sc0 h store -> local L2; flag at MALL)
        if (is_store) {
            const bool act_r = (row0 + sr) < bs_t;
            float hn[4];
            #pragma unroll
            for (int c = 0; c < 4; ++c) hn[c] = ss ? bv[c] : av[c];
            float hv[4];
            #pragma unroll
            for (int c = 0; c < 4; ++c) hv[c] = act_r ? hn[c] : hprev[c];
            if (owner) {
                if (act_r) { hxy0 = hn[0]; hxy1 = hn[1]; }
                else       { hv[0] = hxy0; hv[1] = hxy1; }
            }
            #pragma unroll
            for (int c = 0; c < 4; ++c) hprev[c] = hv[c];
            U64x1 sv;
            #pragma unroll
            for (int c = 0; c < 4; ++c) sv.v[c] = (__bf16)hv[c];
            store_h64(base_n + (size_t)(row0 + sr) * HD + jc, sv.q);
            asm volatile("s_waitcnt vmcnt(0)" ::: "memory");
            __builtin_amdgcn_sched_barrier(0);
            if (lane == 0)
                __hip_atomic_store(&flags[mg * 64 + jb * 4 + w], t + 2,
                                   __ATOMIC_RELAXED, __HIP_MEMORY_SCOPE_AGENT);

            // outputs[t] (off the inter-block critical path)
            float4 q;
            q.x = act_r ? hn[0] : 0.f; q.y = act_r ? hn[1] : 0.f;
            q.z = act_r ? hn[2] : 0.f; q.w = act_r ? hn[3] : 0.f;
            *reinterpret_cast<float4*>(out + (size_t)t * (BM * HD)
                                       + (size_t)(row0 + sr) * HD + jc) = q;
        }
    }

    // ---------------- epilogue ----------------
    // owner cols 0,1 track the exact fp32 xcorr channel (idempotent if active)
    if (owner) { hprev[0] = hxy0; hprev[1] = hxy1; }
    if (is_store) {
        float4 p;
        p.x = hprev[0]; p.y = hprev[1]; p.z = hprev[2]; p.w = hprev[3];
        *reinterpret_cast<float4*>(out + (size_t)TN * BM * HD
                                   + (size_t)(row0 + sr) * HD + jc) = p;
    }
    {
        float* cp = out + (size_t)TN * BM * HD + (size_t)BM * HD;
        #pragma unroll
        for (int f = 0; f < 2; ++f)
            cp[(size_t)(row0 + l15) * HD + j0 + 8 * w + 4 * f + kg] = creg[f];
    }
}

extern "C" void kernel_launch(void* const* d_in, const int* in_sizes, int n_in,
                              void* d_out, int out_size, void* d_ws, size_t ws_size,
                              hipStream_t stream) {
    const float* x_in = (const float*)d_in[0];
    const int*   bs   = (const int*)d_in[1];
    const float* h0   = (const float*)d_in[2];
    const float* c0   = (const float*)d_in[3];
    const float* tau  = (const float*)d_in[4];
    const float* Ww   = (const float*)d_in[5];
    const float* Wb   = (const float*)d_in[6];
    const float* Uw   = (const float*)d_in[7];
    float* out = (float*)d_out;

    int*    flags = (int*)d_ws;                      // 16 groups x 64 flags = 4 KB
    __bf16* hbuf  = (__bf16*)((char*)d_ws + 4096);   // 2 bufs x 256 x 512 bf16 = 512 KB

    (void)hipMemsetAsync(d_ws, 0, 4096, stream);

    hipLaunchKernelGGL(lstm_persist, dim3(256), dim3(256), 0, stream,
                       x_in, bs, h0, c0, tau, Ww, Wb, Uw, out, hbuf, flags);
}